// Round 7
// baseline (446.762 us; speedup 1.0000x reference)
//
#include <hip/hip_runtime.h>

#define DD 256
#define KK 1024
#define HW 4096
#define NROWSZ 65536
#define OUT_Z 16777216
#define OUT_IDX OUT_Z
#define OUT_LOSS (OUT_Z + NROWSZ)

#define MARGIN 2.5e-4f

// ws layout (bytes)
#define WS_ESQ   0          // float[1024]
#define WS_EH    4096       // _Float16[262144] emb fp16 [k][d]
#define WS_LSUM  528384     // double

typedef _Float16 f16x8 __attribute__((ext_vector_type(8)));
typedef float f32x4 __attribute__((ext_vector_type(4)));
union U16x8 { uint4 u; f16x8 h; };
typedef unsigned long long u64;

static __device__ __forceinline__ u64 umin64(u64 a, u64 b) { return a < b ? a : b; }
static __device__ __forceinline__ unsigned fkey(float s) {
    unsigned b = __float_as_uint(s);
    unsigned flip = (unsigned)((int)b >> 31) | 0x80000000u;
    return b ^ flip;
}
static __device__ __forceinline__ float funkey(unsigned k) {
    unsigned b = (k & 0x80000000u) ? (k ^ 0x80000000u) : ~k;
    return __uint_as_float(b);
}
static __device__ __forceinline__ unsigned pk16(float a, float b) {
    _Float16 ha = (_Float16)a, hb = (_Float16)b;
    return (unsigned)__builtin_bit_cast(unsigned short, ha)
         | ((unsigned)__builtin_bit_cast(unsigned short, hb) << 16);
}

// bit-exact numpy pairwise_sum of squares over 256 contiguous floats
static __device__ __forceinline__ float zsq_exact(const float* __restrict__ p) {
    float blk[2];
#pragma unroll
    for (int b2 = 0; b2 < 2; ++b2) {
        const float* q = p + b2 * 128;
        float r[8];
#pragma unroll
        for (int j = 0; j < 8; ++j) r[j] = __fmul_rn(q[j], q[j]);
#pragma unroll
        for (int i = 8; i < 128; i += 8) {
#pragma unroll
            for (int j = 0; j < 8; ++j)
                r[j] = __fadd_rn(r[j], __fmul_rn(q[i + j], q[i + j]));
        }
        blk[b2] = __fadd_rn(__fadd_rn(__fadd_rn(r[0], r[1]), __fadd_rn(r[2], r[3])),
                            __fadd_rn(__fadd_rn(r[4], r[5]), __fadd_rn(r[6], r[7])));
    }
    return __fadd_rn(blk[0], blk[1]);
}

// bit-exact BLAS-model dot: sequential fp32 fmaf, d ascending
static __device__ __forceinline__ float dot_exact(const float* __restrict__ zr,
                                                  const float* __restrict__ er) {
    float a = 0.f;
#pragma unroll 8
    for (int d = 0; d < DD; ++d) a = fmaf(zr[d], er[d], a);
    return a;
}

// ---------------- prep: esq (numpy pairwise-8 exact), eh fp16, init lsum -----------
__global__ void vq_prep(const float* __restrict__ emb, float* __restrict__ esq,
                        uint2* __restrict__ eh2, double* __restrict__ lsum)
{
    const int bid = blockIdx.x;
    const int t = threadIdx.x;
    if (bid == 0 && t == 0) *lsum = 0.0;

    if (bid < 4) {
        int k = bid * 256 + t;
        esq[k] = zsq_exact(emb + (size_t)k * DD);
    } else {
        int tid = (bid - 4) * 256 + t;
        const float4* e4 = (const float4*)emb;
#pragma unroll
        for (int i = 0; i < 16; ++i) {
            int idx = i * 4096 + tid;
            float4 v = e4[idx];
            eh2[idx] = make_uint2(pk16(v.x, v.y), pk16(v.z, v.w));
        }
    }
}

// ---------------- score: MFMA + in-kernel exact resolution + scatter + loss ---------
__launch_bounds__(256, 2)
__global__ void vq_score(const float* __restrict__ z, const float* __restrict__ emb,
                         const _Float16* __restrict__ eh, const float* __restrict__ esq,
                         float* __restrict__ out, double* __restrict__ lsum)
{
    __shared__ __align__(16) float zf[64 * 264];   // 67.6 KB, z fp32 [row][d]
    __shared__ uint2 cand[64][4];
    __shared__ unsigned pairs[512];
    __shared__ u64 res[512];
    __shared__ int ulist[64];
    __shared__ int spos[64], snc[64];
    __shared__ int idxs[64];
    __shared__ int scnt, ucnt;
    __shared__ float wsum[4];
    __shared__ u64 redw[4];

    const int t = threadIdx.x;
    const int lane = t & 63;
    const int w = t >> 6;
    const int col = lane & 15;
    const int quad = lane >> 4;

    const int n0 = blockIdx.x * 64;
    const int b = n0 >> 12;
    const int hw0 = n0 & (HW - 1);
    const float* zbase = z + (size_t)b * DD * HW;

    if (t == 0) { scnt = 0; ucnt = 0; }

    // ---- stage z fp32 -> LDS (coalesced global reads, float4 LDS stores)
    {
        const int r = t & 63, dg = t >> 6;
        const float* src = zbase + hw0 + r + (size_t)(dg * 64) * HW;
        float* dst = &zf[r * 264 + dg * 64];
#pragma unroll 4
        for (int i = 0; i < 16; ++i) {
            float4 v;
            v.x = src[(size_t)(4 * i + 0) * HW];
            v.y = src[(size_t)(4 * i + 1) * HW];
            v.z = src[(size_t)(4 * i + 2) * HW];
            v.w = src[(size_t)(4 * i + 3) * HW];
            *(float4*)&dst[i * 4] = v;
        }
    }
    __syncthreads();

    // ---- A-fragments into registers (fp16 RNE), 128 VGPRs
    U16x8 af[4][8];
#pragma unroll
    for (int nt = 0; nt < 4; ++nt)
#pragma unroll
        for (int ds = 0; ds < 8; ++ds) {
            const float* p = &zf[(nt * 16 + col) * 264 + ds * 32 + quad * 8];
            float4 x0 = *(const float4*)p;
            float4 x1 = *(const float4*)(p + 4);
            af[nt][ds].u = make_uint4(pk16(x0.x, x0.y), pk16(x0.z, x0.w),
                                      pk16(x1.x, x1.y), pk16(x1.z, x1.w));
        }

    // ---- main loop: this wave scans codes [w*256, w*256+256)
    unsigned t1[16], t2[16];
#pragma unroll
    for (int i = 0; i < 16; ++i) { t1[i] = 0xFFFFFFFFu; t2[i] = 0xFFFFFFFFu; }

    const uint4* ehq = (const uint4*)eh;
    const int cbase = w * 256;
    for (int ct = 0; ct < 16; ++ct) {
        const int code = cbase + ct * 16 + col;
        const float eq = esq[code];
        const uint4* bp = ehq + (size_t)code * 32 + quad;
        f32x4 acc[4];
#pragma unroll
        for (int nt = 0; nt < 4; ++nt) acc[nt] = (f32x4)0.0f;
#pragma unroll
        for (int ds = 0; ds < 8; ++ds) {
            U16x8 bf;
            bf.u = bp[ds * 4];
#pragma unroll
            for (int nt = 0; nt < 4; ++nt)
                acc[nt] = __builtin_amdgcn_mfma_f32_16x16x32_f16(af[nt][ds].h, bf.h,
                                                                 acc[nt], 0, 0, 0);
        }
#pragma unroll
        for (int nt = 0; nt < 4; ++nt)
#pragma unroll
            for (int r = 0; r < 4; ++r) {
                float s = __fsub_rn(eq, __fmul_rn(2.0f, acc[nt][r]));
                unsigned key = (fkey(s) & 0xFFFFFC00u) | (unsigned)code;
                int mi = nt * 4 + r;
                unsigned mx = max(t1[mi], key);
                t1[mi] = min(t1[mi], key);
                t2[mi] = min(t2[mi], mx);
            }
    }

    // ---- cross-col (16-lane) top2 merge -> per-wave candidates
#pragma unroll
    for (int mi = 0; mi < 16; ++mi) {
        unsigned a = t1[mi], bb = t2[mi];
#pragma unroll
        for (int off = 1; off < 16; off <<= 1) {
            unsigned o1 = __shfl_xor(a, off, 16);
            unsigned o2 = __shfl_xor(bb, off, 16);
            unsigned mx = max(a, o1);
            a = min(a, o1);
            bb = min(min(bb, o2), mx);
        }
        if (col == 0) {
            int row = (mi >> 2) * 16 + quad * 4 + (mi & 3);
            cand[row][w] = make_uint2(a, bb);
        }
    }
    __syncthreads();

    // ---- merge + margin classification (certain / semi / ultra)
    if (t < 64) {
        unsigned k8[8];
#pragma unroll
        for (int ww = 0; ww < 4; ++ww) {
            uint2 c = cand[t][ww];
            k8[2 * ww] = c.x;
            k8[2 * ww + 1] = c.y;
        }
        unsigned a = k8[0];
#pragma unroll
        for (int i = 1; i < 8; ++i) a = min(a, k8[i]);
        float s1 = funkey(a & 0xFFFFFC00u);
        float thr = __fadd_rn(s1, MARGIN);

        bool ultra = false;
#pragma unroll
        for (int ww = 0; ww < 4; ++ww) {
            float sw2 = funkey(k8[2 * ww + 1] & 0xFFFFFC00u);
            if (sw2 <= thr) ultra = true;
        }
        int nc = 0;
        unsigned codes[8];
#pragma unroll
        for (int i = 0; i < 8; ++i) {
            float si = funkey(k8[i] & 0xFFFFFC00u);
            if (si <= thr) codes[nc++] = k8[i] & 1023u;
        }
        if (ultra) {
            int p = atomicAdd(&ucnt, 1);
            ulist[p] = t;
            idxs[t] = -1;
        } else if (nc > 1) {
            int p = atomicAdd(&scnt, nc);
            spos[t] = p; snc[t] = nc;
            for (int i = 0; i < nc; ++i) pairs[p + i] = ((unsigned)t << 10) | codes[i];
            idxs[t] = -2;
        } else {
            idxs[t] = (int)codes[0];
            out[OUT_IDX + n0 + t] = (float)codes[0];
        }
    }
    __syncthreads();

    // ---- semi: bit-exact rescore of candidate codes (z from LDS, emb from L2)
    {
        const int S = scnt;
        for (int p = t; p < S; p += 256) {
            unsigned pr = pairs[p];
            int row = (int)(pr >> 10);
            int code = (int)(pr & 1023u);
            const float* zr = &zf[row * 264];
            float zq = zsq_exact(zr);
            float dt = dot_exact(zr, emb + (size_t)code * DD);
            float s = __fsub_rn(__fadd_rn(zq, esq[code]), __fmul_rn(2.0f, dt));
            res[p] = ((u64)fkey(s) << 32) | (unsigned)code;
        }
    }
    __syncthreads();
    if (t < 64 && idxs[t] == -2) {
        u64 m = ~0ull;
        int p0 = spos[t], n = snc[t];
        for (int i = 0; i < n; ++i) m = umin64(m, res[p0 + i]);
        int kf = (int)(m & 1023u);
        idxs[t] = kf;
        out[OUT_IDX + n0 + t] = (float)kf;
    }
    __syncthreads();

    // ---- ultra (rare): full 1024-code bit-exact scan, whole block per row
    {
        const int U = ucnt;
        for (int u = 0; u < U; ++u) {
            int row = ulist[u];
            const float* zr = &zf[row * 264];
            float zq = zsq_exact(zr);   // broadcast LDS reads, all threads
            u64 m = ~0ull;
#pragma unroll
            for (int kk = 0; kk < 4; ++kk) {
                int code = kk * 256 + t;
                float dt = dot_exact(zr, emb + (size_t)code * DD);
                float s = __fsub_rn(__fadd_rn(zq, esq[code]), __fmul_rn(2.0f, dt));
                m = umin64(m, ((u64)fkey(s) << 32) | (unsigned)code);
            }
#pragma unroll
            for (int off = 1; off < 64; off <<= 1)
                m = umin64(m, __shfl_xor(m, off, 64));
            if (lane == 0) redw[w] = m;
            __syncthreads();
            if (t == 0) {
                u64 mm = umin64(umin64(redw[0], redw[1]), umin64(redw[2], redw[3]));
                int kf = (int)(mm & 1023u);
                idxs[row] = kf;
                out[OUT_IDX + n0 + row] = (float)kf;
            }
            __syncthreads();
        }
    }

    // ---- scatter z_q + loss partial (z exact from LDS)
    {
        const int rr = t & 63;
        const int dg = t >> 6;
        int idx = idxs[rr];
        const float* erow = emb + (size_t)idx * DD;
        const float* zrow = &zf[rr * 264];
        float* oc = out + (size_t)b * DD * HW + hw0 + rr;
        float lacc = 0.f;
#pragma unroll 4
        for (int dd = 0; dd < 64; ++dd) {
            int d = dg * 64 + dd;
            float e = erow[d];
            float zv = zrow[d];
            oc[(size_t)d * HW] = e;
            float df = e - zv;
            lacc = fmaf(df, df, lacc);
        }
#pragma unroll
        for (int off = 32; off > 0; off >>= 1) lacc += __shfl_down(lacc, off, 64);
        if (lane == 0) wsum[w] = lacc;
    }
    __syncthreads();
    if (t == 0) {
        double tot = (double)wsum[0] + (double)wsum[1] + (double)wsum[2] + (double)wsum[3];
        atomicAdd(lsum, tot);
    }
}

__global__ void vq_final(const double* __restrict__ lsum, float* __restrict__ out)
{
    out[OUT_LOSS] = (float)(0.25 * (lsum[0] / (double)OUT_Z));
}

extern "C" void kernel_launch(void* const* d_in, const int* in_sizes, int n_in,
                              void* d_out, int out_size, void* d_ws, size_t ws_size,
                              hipStream_t stream)
{
    const float* z = (const float*)d_in[0];
    const float* emb = (const float*)d_in[1];
    float* out = (float*)d_out;
    char* w = (char*)d_ws;

    float* esq = (float*)(w + WS_ESQ);
    _Float16* eh = (_Float16*)(w + WS_EH);
    uint2* eh2 = (uint2*)(w + WS_EH);
    double* lsum = (double*)(w + WS_LSUM);

    vq_prep<<<dim3(20), dim3(256), 0, stream>>>(emb, esq, eh2, lsum);
    vq_score<<<dim3(1024), dim3(256), 0, stream>>>(z, emb, eh, esq, out, lsum);
    vq_final<<<dim3(1), dim3(1), 0, stream>>>(lsum, out);
}